// Round 5
// baseline (1052.415 us; speedup 1.0000x reference)
//
#include <hip/hip_runtime.h>
#include <hip/hip_bf16.h>

// Attention4DDownsample R5 — 256-thread blocks (4 waves), 4 blocks/CU.
// prep_weights: fold BN/bias/0.25-scale into bf16 weights + fp32 offset arrays.
// prep_xt:      x fp32 [b][384][49] -> xT bf16 [b][49][384] in ws.
// attn4d:       GEMM B-frags straight from global xT; LDS only for small
//               intermediates (40,192 B). v_local+PV fused (reg-level).

#define DIMC 384
#define NPOS 49
#define NHKD 128
#define DHC  512
#define OUTC 384

// wgt (bf16) element offsets
#define WG_KW  0
#define WG_VW  49152
#define WG_QPW 245760
#define WG_PW  294912
#define W_TOT  491520
// wsf (fp32) element offsets (base = ws byte 983040)
#define F_VLW   0
#define F_KOFF  4608
#define F_QOFF  4736
#define F_VOFF  4864
#define F_VLOFF 5376
#define F_POFF  5888
#define F_TOT   6272
// xT at ws byte offset 1008128; size 2048*49*384*2 = 77,070,336 B

typedef __attribute__((ext_vector_type(8))) __bf16 bf16x8;
typedef __attribute__((ext_vector_type(4))) float f32x4;

static __device__ __forceinline__ __hip_bfloat16 f2b(float x) { return __float2bfloat16(x); }
static __device__ __forceinline__ float b2f(__hip_bfloat16 x) { return __bfloat162float(x); }
static __device__ __forceinline__ bf16x8 ld8(const __hip_bfloat16* p) { return *(const bf16x8*)p; }
static __device__ __forceinline__ f32x4 fzero() {
  f32x4 z; z[0] = 0.f; z[1] = 0.f; z[2] = 0.f; z[3] = 0.f; return z;
}
static __device__ __forceinline__ bf16x8 bzero() {
  bf16x8 z;
  #pragma unroll
  for (int j = 0; j < 8; ++j) z[j] = (__bf16)0.0f;
  return z;
}
static __device__ __forceinline__ float bn_scale(const float* bn, int C, int ch) {
  return bn[ch] * rsqrtf(bn[3 * C + ch] + 1e-5f);
}
static __device__ __forceinline__ float bn_off(const float* bn, int C, int ch, float convb) {
  float s = bn_scale(bn, C, ch);
  return bn[C + ch] + (convb - bn[2 * C + ch]) * s;
}

// ---------------- prep 1: fold BN into weights ----------------
__global__ void prep_weights(
    const float* __restrict__ qpw, const float* __restrict__ qpb, const float* __restrict__ qbn,
    const float* __restrict__ kw,  const float* __restrict__ kb,  const float* __restrict__ kbn,
    const float* __restrict__ vw,  const float* __restrict__ vb,  const float* __restrict__ vbn,
    const float* __restrict__ vlw, const float* __restrict__ vlb, const float* __restrict__ vlbn,
    const float* __restrict__ pw,  const float* __restrict__ pb,  const float* __restrict__ pbn,
    __hip_bfloat16* __restrict__ wgt, float* __restrict__ wsf)
{
  const int i0 = blockIdx.x * blockDim.x + threadIdx.x;
  const int st = gridDim.x * blockDim.x;
  for (int i = i0; i < W_TOT; i += st) {
    float w, s;
    if (i < WG_VW)        { int oc = i / 384;                w = kw[i];             s = bn_scale(kbn, NHKD, oc); }
    else if (i < WG_QPW)  { int j = i - WG_VW;  int oc = j / 384; w = vw[j];        s = bn_scale(vbn, DHC, oc); }
    else if (i < WG_PW)   { int j = i - WG_QPW; int oc = j / 384; w = qpw[j];       s = 0.25f * bn_scale(qbn, NHKD, oc); }
    else                  { int j = i - WG_PW;  int oc = j / 512; w = pw[j];        s = bn_scale(pbn, OUTC, oc); }
    wgt[i] = f2b(w * s);
  }
  for (int i = i0; i < 4608; i += st)
    wsf[F_VLW + i] = vlw[i] * bn_scale(vlbn, DHC, i / 9);
  for (int i = i0; i < 512; i += st) {
    if (i < NHKD) {
      wsf[F_KOFF + i] = bn_off(kbn, NHKD, i, kb[i]);
      wsf[F_QOFF + i] = 0.25f * bn_off(qbn, NHKD, i, qpb[i]);
    }
    wsf[F_VOFF + i]  = bn_off(vbn, DHC, i, vb[i]);
    wsf[F_VLOFF + i] = bn_off(vlbn, DHC, i, vlb[i]);
    if (i < OUTC) wsf[F_POFF + i] = bn_off(pbn, OUTC, i, pb[i]);
  }
}

// ---------------- prep 2: transpose x -> xT bf16 ----------------
__global__ __launch_bounds__(256) void prep_xt(const float* __restrict__ x,
                                               __hip_bfloat16* __restrict__ xT) {
  __shared__ __bf16 xls[18816];            // [c 384][n 49]
  const int b = blockIdx.x, tid = threadIdx.x;
  const f32x4* xg = (const f32x4*)(x + (size_t)b * 18816);
  for (int i = tid; i < 4704; i += 256) {
    f32x4 v = xg[i];
    #pragma unroll
    for (int j = 0; j < 4; ++j) xls[i * 4 + j] = (__bf16)v[j];
  }
  __syncthreads();
  __hip_bfloat16* xo = xT + (size_t)b * 18816;   // [n 49][c 384]
  for (int j = tid; j < 2352; j += 256) {
    const int n = j / 48, c0 = (j - n * 48) * 8;
    bf16x8 v;
    #pragma unroll
    for (int t = 0; t < 8; ++t) v[t] = xls[(c0 + t) * 49 + n];
    *(bf16x8*)&xo[n * 384 + c0] = v;
  }
}

// LDS map (bf16 elems), total 20096 = 40,192 B -> 4 blocks/CU:
//  R0 @0     : kt [49][136] (6664)  then rout [16][520] (8320)       -> 8320
//  R1 @8320  : qsm [8][16][32] (4096) then vsm [64][72] (4608)       -> 4608
//  R2 @12928 : qin [16][392] (6272) then attnS [8][16][56] (7168)    -> 7168
__global__ __launch_bounds__(256, 4) void attn4d_kernel(
    const float* __restrict__ qlw, const float* __restrict__ qlb,
    const float* __restrict__ ab,  const int* __restrict__ bidx,
    const __hip_bfloat16* __restrict__ wgt, const float* __restrict__ wsf,
    const __hip_bfloat16* __restrict__ xT,
    int n_off, float* __restrict__ out)
{
  __shared__ __align__(16) __hip_bfloat16 smem[20096];
  __hip_bfloat16* kt    = smem;            // [nk<49][oc] stride 136
  __hip_bfloat16* rout  = smem;            // [nq][d] stride 520
  __hip_bfloat16* qsm   = smem + 8320;     // [h][nq][kd32] stride 32 (kd16..31 = 0)
  __hip_bfloat16* vsm   = smem + 8320;     // [64][72] per-chunk v
  __hip_bfloat16* qin   = smem + 12928;    // [nq][c] stride 392
  __hip_bfloat16* attnS = smem + 12928;    // [h][nq][nk] stride 56 (49..55 = 0)

  const __hip_bfloat16* kwb  = wgt + WG_KW;
  const __hip_bfloat16* vwb  = wgt + WG_VW;
  const __hip_bfloat16* qpwb = wgt + WG_QPW;
  const __hip_bfloat16* pwb  = wgt + WG_PW;
  const float* vlwf  = wsf + F_VLW;
  const float* koff  = wsf + F_KOFF;
  const float* qoff  = wsf + F_QOFF;
  const float* voff  = wsf + F_VOFF;
  const float* vloff = wsf + F_VLOFF;
  const float* poff  = wsf + F_POFF;

  const int tid  = threadIdx.x;
  const int lane = tid & 63;
  const int wave = tid >> 6;     // 0..3
  const int quad = lane >> 4;
  const int l15  = lane & 15;
  const int b    = blockIdx.x;
  const __hip_bfloat16* xb = xT + (size_t)b * 18816;   // [49][384]

  // ---- PA: qin[nq][c] = dw3x3 s2 p1 (local_q) + avgpool2 (zero-padded)
  for (int c = tid; c < DIMC; c += 256) {
    float xv[49];
    #pragma unroll
    for (int n = 0; n < 49; ++n) xv[n] = b2f(xb[n * 384 + c]);
    float wq[9];
    #pragma unroll
    for (int j = 0; j < 9; ++j) wq[j] = qlw[c * 9 + j];
    const float cb = qlb[c];
    #pragma unroll
    for (int oh = 0; oh < 4; ++oh) {
      #pragma unroll
      for (int ow = 0; ow < 4; ++ow) {
        float a = cb;
        #pragma unroll
        for (int kh = 0; kh < 3; ++kh) {
          const int ih = 2 * oh - 1 + kh;
          if (ih < 0 || ih > 6) continue;
          #pragma unroll
          for (int kwi = 0; kwi < 3; ++kwi) {
            const int iw = 2 * ow - 1 + kwi;
            if (iw < 0 || iw > 6) continue;
            a += wq[kh * 3 + kwi] * xv[ih * 7 + iw];
          }
        }
        if (oh < 3 && ow < 3)
          a += 0.25f * (xv[(2*oh)*7 + 2*ow] + xv[(2*oh)*7 + 2*ow + 1] +
                        xv[(2*oh+1)*7 + 2*ow] + xv[(2*oh+1)*7 + 2*ow + 1]);
        qin[(oh * 4 + ow) * 392 + c] = f2b(a);
      }
    }
  }

  // ---- PBk: k GEMM (128 ch), B-frags from global xT. wave -> 2 M-tiles.
  {
    f32x4 acc[2][4];
    #pragma unroll
    for (int i = 0; i < 2; ++i)
      #pragma unroll
      for (int nt = 0; nt < 4; ++nt) acc[i][nt] = fzero();
    for (int ks = 0; ks < 12; ++ks) {
      const int c0 = ks * 32 + quad * 8;
      bf16x8 bfr[4];
      #pragma unroll
      for (int nt = 0; nt < 4; ++nt) {
        const int n = nt * 16 + l15;
        bfr[nt] = (n < 49) ? ld8(&xb[n * 384 + c0]) : bzero();
      }
      #pragma unroll
      for (int i = 0; i < 2; ++i) {
        bf16x8 a = ld8(&kwb[((wave * 2 + i) * 16 + l15) * 384 + c0]);
        #pragma unroll
        for (int nt = 0; nt < 4; ++nt)
          acc[i][nt] = __builtin_amdgcn_mfma_f32_16x16x32_bf16(a, bfr[nt], acc[i][nt], 0, 0, 0);
      }
    }
    #pragma unroll
    for (int i = 0; i < 2; ++i)
      #pragma unroll
      for (int r = 0; r < 4; ++r) {
        const int oc = (wave * 2 + i) * 16 + quad * 4 + r;
        const float o = koff[oc];
        #pragma unroll
        for (int nt = 0; nt < 4; ++nt) {
          const int n = nt * 16 + l15;
          if (n < 49) kt[n * 136 + oc] = f2b(acc[i][nt][r] + o);
        }
      }
  }
  __syncthreads();   // qin + kt ready

  // ---- PC: q GEMM -> qsm[h][nq][kd], kd16..31 zeroed (A-frag pad)
  {
    f32x4 acc[2];
    acc[0] = fzero(); acc[1] = fzero();
    for (int ks = 0; ks < 12; ++ks) {
      const int c0 = ks * 32 + quad * 8;
      bf16x8 bv = ld8(&qin[l15 * 392 + c0]);
      #pragma unroll
      for (int i = 0; i < 2; ++i) {
        bf16x8 av = ld8(&qpwb[((wave * 2 + i) * 16 + l15) * 384 + c0]);
        acc[i] = __builtin_amdgcn_mfma_f32_16x16x32_bf16(av, bv, acc[i], 0, 0, 0);
      }
    }
    #pragma unroll
    for (int i = 0; i < 2; ++i)
      #pragma unroll
      for (int r = 0; r < 4; ++r) {
        const int oc = (wave * 2 + i) * 16 + quad * 4 + r;
        const int h = oc >> 4, kd = oc & 15;
        qsm[h * 512 + l15 * 32 + kd] = f2b(acc[i][r] + qoff[oc]);
        qsm[h * 512 + l15 * 32 + kd + 16] = f2b(0.f);
      }
  }
  __syncthreads();   // qsm ready

  // ---- PD: logits (0.25 pre-folded) + bias, softmax -> attnS. 2 heads/wave.
  #pragma unroll
  for (int hh = 0; hh < 2; ++hh) {
    const int h = wave * 2 + hh;
    bf16x8 av = ld8(&qsm[h * 512 + l15 * 32 + quad * 8]);
    float p[4][4];
    #pragma unroll
    for (int t = 0; t < 4; ++t) {
      bf16x8 bv = bzero();
      if (quad < 2) bv = ld8(&kt[(t * 16 + l15) * 136 + h * 16 + quad * 8]);
      f32x4 lg = __builtin_amdgcn_mfma_f32_16x16x32_bf16(av, bv, fzero(), 0, 0, 0);
      #pragma unroll
      for (int r = 0; r < 4; ++r) {
        const int nq = quad * 4 + r;
        const int nk = t * 16 + l15;
        p[t][r] = (nk < 49) ? (lg[r] + ab[h * n_off + bidx[nq * 49 + nk]]) : -30000.f;
      }
    }
    #pragma unroll
    for (int r = 0; r < 4; ++r) {
      float m = fmaxf(fmaxf(p[0][r], p[1][r]), fmaxf(p[2][r], p[3][r]));
      m = fmaxf(m, __shfl_xor(m, 1));
      m = fmaxf(m, __shfl_xor(m, 2));
      m = fmaxf(m, __shfl_xor(m, 4));
      m = fmaxf(m, __shfl_xor(m, 8));
      float e[4], sum = 0.f;
      #pragma unroll
      for (int t = 0; t < 4; ++t) { e[t] = __expf(p[t][r] - m); sum += e[t]; }
      sum += __shfl_xor(sum, 1);
      sum += __shfl_xor(sum, 2);
      sum += __shfl_xor(sum, 4);
      sum += __shfl_xor(sum, 8);
      const float inv = 1.f / sum;
      #pragma unroll
      for (int t = 0; t < 4; ++t) p[t][r] = e[t] * inv;   // exact 0 for nk>=49
    }
    #pragma unroll
    for (int r = 0; r < 4; ++r) {
      const int nq = quad * 4 + r;
      #pragma unroll
      for (int t = 0; t < 4; ++t) {
        const int nk = t * 16 + l15;
        if (nk < 56) attnS[h * 896 + nq * 56 + nk] = f2b(p[t][r]);
      }
    }
  }
  __syncthreads();   // attnS ready (kt dead, qin dead, qsm dead)

  // ---- 8 chunks of 64 v-channels (= head c): vGEMM -> fused v_local+PV
  for (int c = 0; c < 8; ++c) {
    {   // vGEMM: wave -> 1 M-tile (16 ch), 4 N-tiles, K=384
      f32x4 acc[4];
      #pragma unroll
      for (int nt = 0; nt < 4; ++nt) acc[nt] = fzero();
      for (int ks = 0; ks < 12; ++ks) {
        const int c0 = ks * 32 + quad * 8;
        bf16x8 a = ld8(&vwb[(c * 64 + wave * 16 + l15) * 384 + c0]);
        #pragma unroll
        for (int nt = 0; nt < 4; ++nt) {
          const int n = nt * 16 + l15;
          bf16x8 bv = (n < 49) ? ld8(&xb[n * 384 + c0]) : bzero();
          acc[nt] = __builtin_amdgcn_mfma_f32_16x16x32_bf16(a, bv, acc[nt], 0, 0, 0);
        }
      }
      #pragma unroll
      for (int r = 0; r < 4; ++r) {
        const int ocl = wave * 16 + quad * 4 + r;
        const float o = voff[c * 64 + ocl];
        #pragma unroll
        for (int nt = 0; nt < 4; ++nt)
          vsm[ocl * 72 + nt * 16 + l15] = f2b(acc[nt][r] + o);
      }
    }
    __syncthreads();   // vsm ready

    {   // fused: PV (regs) + v_local (regs) -> rout = relu(xa + vloc)
      f32x4 acc = fzero();
      #pragma unroll
      for (int ks = 0; ks < 2; ++ks) {
        const int k0 = ks * 32 + quad * 8;
        bf16x8 av = ld8(&vsm[(wave * 16 + l15) * 72 + k0]);
        bf16x8 bv = (k0 < 56) ? ld8(&attnS[c * 896 + l15 * 56 + k0]) : bzero();
        acc = __builtin_amdgcn_mfma_f32_16x16x32_bf16(av, bv, acc, 0, 0, 0);
      }
      const int pos = l15, oh = pos >> 2, ow = pos & 3;
      #pragma unroll
      for (int r = 0; r < 4; ++r) {
        const int dl = wave * 16 + quad * 4 + r;   // channel within chunk
        const int ch = c * 64 + dl;
        float a = 0.f;
        #pragma unroll
        for (int kh = 0; kh < 3; ++kh) {
          const int ih = 2 * oh - 1 + kh;
          if (ih < 0 || ih > 6) continue;
          #pragma unroll
          for (int kwi = 0; kwi < 3; ++kwi) {
            const int iw = 2 * ow - 1 + kwi;
            if (iw < 0 || iw > 6) continue;
            a += vlwf[ch * 9 + kh * 3 + kwi] * b2f(vsm[dl * 72 + ih * 7 + iw]);
          }
        }
        a += vloff[ch];
        rout[pos * 520 + ch] = f2b(fmaxf(acc[r] + a, 0.f));
      }
    }
    __syncthreads();   // rout chunk written; vsm reusable
  }

  // ---- PF: proj GEMM — out[b][oc][pos] = pw' @ rout + poff (fp32)
  {
    f32x4 acc[6];
    #pragma unroll
    for (int t = 0; t < 6; ++t) acc[t] = fzero();
    for (int ks = 0; ks < 16; ++ks) {
      const int c0 = ks * 32 + quad * 8;
      bf16x8 bv = ld8(&rout[l15 * 520 + c0]);
      #pragma unroll
      for (int t = 0; t < 6; ++t) {
        bf16x8 av = ld8(&pwb[((wave * 6 + t) * 16 + l15) * 512 + c0]);
        acc[t] = __builtin_amdgcn_mfma_f32_16x16x32_bf16(av, bv, acc[t], 0, 0, 0);
      }
    }
    float* outb = out + (size_t)b * (OUTC * 16);
    #pragma unroll
    for (int t = 0; t < 6; ++t)
      #pragma unroll
      for (int r = 0; r < 4; ++r) {
        const int oc = (wave * 6 + t) * 16 + quad * 4 + r;
        outb[oc * 16 + l15] = acc[t][r] + poff[oc];
      }
  }
}

extern "C" void kernel_launch(void* const* d_in, const int* in_sizes, int n_in,
                              void* d_out, int out_size, void* d_ws, size_t ws_size,
                              hipStream_t stream) {
  const float* x    = (const float*)d_in[0];
  const float* qlw  = (const float*)d_in[1];
  const float* qlb  = (const float*)d_in[2];
  const float* qpw  = (const float*)d_in[3];
  const float* qpb  = (const float*)d_in[4];
  const float* qbn  = (const float*)d_in[5];
  const float* kw   = (const float*)d_in[6];
  const float* kb   = (const float*)d_in[7];
  const float* kbn  = (const float*)d_in[8];
  const float* vw   = (const float*)d_in[9];
  const float* vb   = (const float*)d_in[10];
  const float* vbn  = (const float*)d_in[11];
  const float* vlw  = (const float*)d_in[12];
  const float* vlb  = (const float*)d_in[13];
  const float* vlbn = (const float*)d_in[14];
  const float* pw   = (const float*)d_in[15];
  const float* pb   = (const float*)d_in[16];
  const float* pbn  = (const float*)d_in[17];
  const float* ab   = (const float*)d_in[18];
  const int*   bidx = (const int*)d_in[19];
  const int n_off = in_sizes[18] / 8;
  const int Bn = in_sizes[0] / (DIMC * NPOS);   // 2048

  char* wsc = (char*)d_ws;
  __hip_bfloat16* wgt = (__hip_bfloat16*)wsc;                  // 983,040 B
  float*          wsf = (float*)(wsc + 983040);                // 25,088 B
  __hip_bfloat16* xT  = (__hip_bfloat16*)(wsc + 1008128);      // 77,070,336 B

  prep_weights<<<256, 256, 0, stream>>>(qpw, qpb, qbn, kw, kb, kbn, vw, vb, vbn,
                                        vlw, vlb, vlbn, pw, pb, pbn, wgt, wsf);
  prep_xt<<<Bn, 256, 0, stream>>>(x, xT);
  attn4d_kernel<<<Bn, 256, 0, stream>>>(qlw, qlb, ab, bidx, wgt, wsf, xT,
                                        n_off, (float*)d_out);
}